// Round 10
// baseline (205.081 us; speedup 1.0000x reference)
//
#include <hip/hip_runtime.h>
#include <cstdint>
#include <cstddef>

#define GLOBAL_AS __attribute__((address_space(1)))
#define LDS_AS __attribute__((address_space(3)))

typedef unsigned short u16;
typedef unsigned int u32;
typedef __bf16 bf16x8 __attribute__((ext_vector_type(8)));
typedef float f32x4 __attribute__((ext_vector_type(4)));

static constexpr int CDIM = 768;
static constexpr int NROWS = 8192;   // B*Lq == B*H*W
static constexpr int KS1 = 4;        // split-K for the off/attn GEMM
// Inputs/outputs are f32 [measured: r1-r2 bf16-interpretation -> NaN; r3-r8 detect->f32 path passes]

__device__ __forceinline__ u16 f2bf(float f) {
  union { float f; u32 u; } v; v.f = f;
  return (u16)((v.u + 0x7fffu + ((v.u >> 16) & 1u)) >> 16);   // RNE
}
__device__ __forceinline__ float bf2f(u16 h) {
  union { u32 u; float f; } v; v.u = ((u32)h) << 16;
  return v.f;
}
// async 16B/lane global->LDS; LDS dest = wave-uniform base + lane*16 [m97]
__device__ __forceinline__ void load_lds16(const u16* g, u16* l) {
  __builtin_amdgcn_global_load_lds((const GLOBAL_AS u32*)g, (LDS_AS u32*)l, 16, 0, 0);
}

// ---------------- pre: LN rows (blocks 0..16383) + weight prep (blocks 16384..18111) ----------------
__global__ __launch_bounds__(192) void pre_kernel(
    const float* __restrict__ x, const float* __restrict__ feat,
    const float* __restrict__ qw, const float* __restrict__ qb,
    const float* __restrict__ fw, const float* __restrict__ fb,
    const float* __restrict__ wv_, const float* __restrict__ wo_,
    const float* __restrict__ woff, const float* __restrict__ wattn,
    u16* __restrict__ qout, u16* __restrict__ fout,
    u16* __restrict__ wvT, u16* __restrict__ woT, u16* __restrict__ woaT) {
  __shared__ __align__(8) char shbuf[32*33*2];
  const int bx = blockIdx.x;
  const int t = threadIdx.x;
  if (bx < 2*NROWS) {                     // ---- LayerNorm ----
    const float *src, *w, *b; u16* dst; size_t base;
    if (bx < NROWS) { src = x; base = (size_t)bx*CDIM; w = qw; b = qb; dst = qout + base; }
    else { int r2 = bx - NROWS; src = feat; base = (size_t)r2*CDIM; w = fw; b = fb; dst = fout + (size_t)r2*CDIM; }
    float4 q = ((const float4*)(src + base))[t];
    float v[4] = {q.x, q.y, q.z, q.w};
    float s = v[0]+v[1]+v[2]+v[3];
    float sq = v[0]*v[0]+v[1]*v[1]+v[2]*v[2]+v[3]*v[3];
    #pragma unroll
    for (int m = 32; m >= 1; m >>= 1) { s += __shfl_xor(s, m, 64); sq += __shfl_xor(sq, m, 64); }
    float* red = (float*)shbuf;
    int lane = t & 63, wv = t >> 6;
    if (lane == 0) { red[wv] = s; red[wv+3] = sq; }
    __syncthreads();
    s  = red[0]+red[1]+red[2];
    sq = red[3]+red[4]+red[5];
    float mean = s * (1.f/768.f);
    float var  = fmaxf(sq * (1.f/768.f) - mean*mean, 0.f);
    float inv  = rsqrtf(var + 1e-6f);
    float4 wq_ = ((const float4*)w)[t];
    float4 bq_ = ((const float4*)b)[t];
    u16 o[4];
    o[0] = f2bf((v[0]-mean)*inv*wq_.x + bq_.x);
    o[1] = f2bf((v[1]-mean)*inv*wq_.y + bq_.y);
    o[2] = f2bf((v[2]-mean)*inv*wq_.z + bq_.z);
    o[3] = f2bf((v[3]-mean)*inv*wq_.w + bq_.w);
    *(ushort4*)(dst + t*4) = make_ushort4(o[0], o[1], o[2], o[3]);
    return;
  }
  const int pid = bx - 2*NROWS;           // 0..1727
  const int z   = pid / 576;              // 0,1,2
  const int rem = pid - z*576;            // 0..575
  if (z == 2) {                           // ---- build [128][768] woaT = [w_off|w_attn|0]^T ----
    int idx = rem*192 + t;
    if (idx >= 128*CDIM) return;
    int n = idx / CDIM, k = idx - n*CDIM;
    float v = 0.f;
    if (n < 48)      v = woff[(size_t)k*48 + n];
    else if (n < 72) v = wattn[(size_t)k*24 + (n-48)];
    woaT[idx] = f2bf(v);
    return;
  }
  // ---- transpose w_value / w_out [K][N] -> [N][K] to bf16 ----
  u16* tile = (u16*)shbuf;                // [32][33]
  const float* in = z ? wo_ : wv_;
  u16* out        = z ? woT : wvT;
  int bn = (rem % 24) * 32;
  int bk = (rem / 24) * 32;
  int tx = t & 31, ty = t >> 5;           // ty 0..5
  for (int i = ty; i < 32; i += 6)
    tile[i*33 + tx] = f2bf(in[(size_t)(bk+i)*CDIM + bn + tx]);
  __syncthreads();
  for (int i = ty; i < 32; i += 6)
    out[(size_t)(bn+i)*CDIM + bk + tx] = tile[tx*33 + i];
}

// ---------------- fused GEMM 0+1: grid (64, 14) ----------------
// y<6 : value GEMM  C=A_f*wvT^T tile 128x128, full K, EPI0 bf16+b_value
// y>=6: off/attn GEMM A_q*woaT^T tile 128x64, n0=((y-6)&1)*64, split-K z=(y-6)>>1 (K-chunk 192),
//       EPI1 f32 partials [z][8192][72], bias folded into z==0
__global__ __launch_bounds__(256) void gemm01(
    const u16* __restrict__ Af, const u16* __restrict__ Aq,
    const u16* __restrict__ wvT, const u16* __restrict__ woaT,
    u16* __restrict__ val_bf, float* __restrict__ offawp,
    const float* __restrict__ b_value, const float* __restrict__ b_off,
    const float* __restrict__ b_attn) {
  __shared__ __align__(16) u16 smem[16384];  // 32 KB
  const int m0 = blockIdx.x * 128;
  const int t = threadIdx.x, lane = t & 63, wv = t >> 6;
  const int lrow = lane >> 2;
  const int lcol = (lane & 3) * 8;
  const int kc   = (lane >> 4) * 8;
  const int r0 = (lane >> 4) * 4;    // C/D: col=lane&15, row=(lane>>4)*4+reg  [m89/m91]
  const int c  = lane & 15;

  if (blockIdx.y < 6) {
    // ===== value GEMM, 128x128 tile, BK=64 dual-panel =====
    u16* As = smem;            // panel p at +p*4096, [row][32]
    u16* Bs = smem + 8192;     // panel p at +p*4096
    u16* Cs = smem;            // [128][128] epilogue (32 KB)
    const int n0 = blockIdx.y * 128;
    const int wm = wv & 1, wn = wv >> 1;
    f32x4 acc[4][4] = {};
    for (int k0 = 0; k0 < CDIM; k0 += 64) {
      #pragma unroll
      for (int j = 0; j < 4; ++j) {                // A: 16 1KB segs (2 panels x 8)
        int g = wv*4 + j, p = g >> 3, s = g & 7;
        load_lds16(Af + (size_t)(m0 + s*16 + lrow)*CDIM + k0 + p*32 + lcol,
                   As + p*4096 + s*512);
      }
      #pragma unroll
      for (int j = 0; j < 4; ++j) {                // B: 16 segs
        int g = wv*4 + j, p = g >> 3, s = g & 7;
        load_lds16(wvT + (size_t)(n0 + s*16 + lrow)*CDIM + k0 + p*32 + lcol,
                   Bs + p*4096 + s*512);
      }
      __syncthreads();
      #pragma unroll
      for (int u = 0; u < 2; ++u) {
        bf16x8 af[4], bfr[4];
        #pragma unroll
        for (int i = 0; i < 4; ++i)
          af[i]  = *(const bf16x8*)(As + u*4096 + (wm*64 + i*16 + (lane & 15))*32 + kc);
        #pragma unroll
        for (int j = 0; j < 4; ++j)
          bfr[j] = *(const bf16x8*)(Bs + u*4096 + (wn*64 + j*16 + (lane & 15))*32 + kc);
        #pragma unroll
        for (int i = 0; i < 4; ++i)
          #pragma unroll
          for (int j = 0; j < 4; ++j)
            acc[i][j] = __builtin_amdgcn_mfma_f32_16x16x32_bf16(af[i], bfr[j], acc[i][j], 0, 0, 0);
      }
      __syncthreads();
    }
    #pragma unroll
    for (int i = 0; i < 4; ++i)
      #pragma unroll
      for (int j = 0; j < 4; ++j) {
        int col = wn*64 + j*16 + c;
        float bb = b_value[n0 + col];
        #pragma unroll
        for (int r = 0; r < 4; ++r)
          Cs[(wm*64 + i*16 + r0 + r)*128 + col] = f2bf(acc[i][j][r] + bb);
      }
    __syncthreads();
    #pragma unroll
    for (int it = 0; it < 8; ++it) {
      int idx = it*256 + t;             // 0..2047, 16B each -> 128x128 u16
      int row = idx >> 4, colb = (idx & 15) * 8;
      *(bf16x8*)(val_bf + (size_t)(m0 + row)*CDIM + n0 + colb) = *(const bf16x8*)(Cs + row*128 + colb);
    }
    return;
  }

  // ===== off/attn GEMM, 128x64 tile, split-K =====
  u16* As = smem;            // 2 panels x 4096
  u16* Bs = smem + 8192;     // 2 panels x 2048
  const int g  = blockIdx.y - 6;
  const int n0 = (g & 1) * 64;
  const int zz = g >> 1;
  const int kbase = zz * (CDIM / KS1);
  const int kend  = kbase + CDIM / KS1;
  const int wm = wv & 1, wn = wv >> 1;
  f32x4 acc[4][2] = {};
  for (int k0 = kbase; k0 < kend; k0 += 64) {
    #pragma unroll
    for (int j = 0; j < 4; ++j) {
      int gg = wv*4 + j, p = gg >> 3, s = gg & 7;
      load_lds16(Aq + (size_t)(m0 + s*16 + lrow)*CDIM + k0 + p*32 + lcol,
                 As + p*4096 + s*512);
    }
    #pragma unroll
    for (int j = 0; j < 2; ++j) {
      int gg = wv*2 + j, p = gg >> 2, s = gg & 3;
      load_lds16(woaT + (size_t)(n0 + s*16 + lrow)*CDIM + k0 + p*32 + lcol,
                 Bs + p*2048 + s*512);
    }
    __syncthreads();
    #pragma unroll
    for (int u = 0; u < 2; ++u) {
      bf16x8 af[4], bfr[2];
      #pragma unroll
      for (int i = 0; i < 4; ++i)
        af[i]  = *(const bf16x8*)(As + u*4096 + (wm*64 + i*16 + (lane & 15))*32 + kc);
      #pragma unroll
      for (int j = 0; j < 2; ++j)
        bfr[j] = *(const bf16x8*)(Bs + u*2048 + (wn*32 + j*16 + (lane & 15))*32 + kc);
      #pragma unroll
      for (int i = 0; i < 4; ++i)
        #pragma unroll
        for (int j = 0; j < 2; ++j)
          acc[i][j] = __builtin_amdgcn_mfma_f32_16x16x32_bf16(af[i], bfr[j], acc[i][j], 0, 0, 0);
    }
    __syncthreads();
  }
  float* op = offawp + (size_t)zz * NROWS * 72;
  #pragma unroll
  for (int i = 0; i < 4; ++i)
    #pragma unroll
    for (int j = 0; j < 2; ++j) {
      int col = n0 + wn*32 + j*16 + c;
      if (col < 72) {
        float bb = 0.f;
        if (zz == 0) bb = (col < 48) ? b_off[col] : b_attn[col-48];
        #pragma unroll
        for (int r = 0; r < 4; ++r)
          op[(size_t)(m0 + wm*64 + i*16 + r0 + r)*72 + col] = acc[i][j][r] + bb;
      }
    }
}

// ---------------- output GEMM: 128x128 tile, out = x + gamma*(C + b_out), f32 ----------------
__global__ __launch_bounds__(256) void gemm2(
    const u16* __restrict__ A, const u16* __restrict__ Bt, float* __restrict__ Cout,
    const float* __restrict__ bias0, const float* __restrict__ xres,
    const float* __restrict__ gammap) {
  __shared__ __align__(16) u16 smem[16384];
  u16* As = smem;
  u16* Bs = smem + 8192;
  u16* Cs = smem;
  const int m0 = blockIdx.x * 128;
  const int n0 = blockIdx.y * 128;
  const int t = threadIdx.x, lane = t & 63, wv = t >> 6;
  const int wm = wv & 1, wn = wv >> 1;
  const int lrow = lane >> 2;
  const int lcol = (lane & 3) * 8;
  const int kc   = (lane >> 4) * 8;
  f32x4 acc[4][4] = {};

  for (int k0 = 0; k0 < CDIM; k0 += 64) {
    #pragma unroll
    for (int j = 0; j < 4; ++j) {
      int g = wv*4 + j, p = g >> 3, s = g & 7;
      load_lds16(A + (size_t)(m0 + s*16 + lrow)*CDIM + k0 + p*32 + lcol,
                 As + p*4096 + s*512);
    }
    #pragma unroll
    for (int j = 0; j < 4; ++j) {
      int g = wv*4 + j, p = g >> 3, s = g & 7;
      load_lds16(Bt + (size_t)(n0 + s*16 + lrow)*CDIM + k0 + p*32 + lcol,
                 Bs + p*4096 + s*512);
    }
    __syncthreads();
    #pragma unroll
    for (int u = 0; u < 2; ++u) {
      bf16x8 af[4], bfr[4];
      #pragma unroll
      for (int i = 0; i < 4; ++i)
        af[i]  = *(const bf16x8*)(As + u*4096 + (wm*64 + i*16 + (lane & 15))*32 + kc);
      #pragma unroll
      for (int j = 0; j < 4; ++j)
        bfr[j] = *(const bf16x8*)(Bs + u*4096 + (wn*64 + j*16 + (lane & 15))*32 + kc);
      #pragma unroll
      for (int i = 0; i < 4; ++i)
        #pragma unroll
        for (int j = 0; j < 4; ++j)
          acc[i][j] = __builtin_amdgcn_mfma_f32_16x16x32_bf16(af[i], bfr[j], acc[i][j], 0, 0, 0);
    }
    __syncthreads();
  }

  const int r0 = (lane >> 4) * 4;
  const int c  = lane & 15;
  #pragma unroll
  for (int i = 0; i < 4; ++i)
    #pragma unroll
    for (int j = 0; j < 4; ++j) {
      int col = wn*64 + j*16 + c;
      float bb = bias0[n0 + col];
      #pragma unroll
      for (int r = 0; r < 4; ++r)
        Cs[(wm*64 + i*16 + r0 + r)*128 + col] = f2bf(acc[i][j][r] + bb);
    }
  __syncthreads();
  #pragma unroll
  for (int it = 0; it < 8; ++it) {
    int idx = it*256 + t;               // 0..2047
    int row = idx >> 4, colb = (idx & 15) * 8;
    size_t gbase = (size_t)(m0 + row)*CDIM + n0 + colb;
    const u16* cp = Cs + row*128 + colb;
    const float* xp = xres + gbase;
    const float* gp = gammap + n0 + colb;
    float4 x0 = *(const float4*)xp,  x1 = *(const float4*)(xp + 4);
    float4 g0 = *(const float4*)gp,  g1 = *(const float4*)(gp + 4);
    float4 o0, o1;
    o0.x = x0.x + g0.x*bf2f(cp[0]); o0.y = x0.y + g0.y*bf2f(cp[1]);
    o0.z = x0.z + g0.z*bf2f(cp[2]); o0.w = x0.w + g0.w*bf2f(cp[3]);
    o1.x = x1.x + g1.x*bf2f(cp[4]); o1.y = x1.y + g1.y*bf2f(cp[5]);
    o1.z = x1.z + g1.z*bf2f(cp[6]); o1.w = x1.w + g1.w*bf2f(cp[7]);
    *(float4*)(Cout + gbase)     = o0;
    *(float4*)(Cout + gbase + 4) = o1;
  }
}

// ---------------- deformable sampling: wave handles 2 heads of one row, 32-load burst ----------------
__global__ __launch_bounds__(256) void sample_kernel(
    const u16* __restrict__ value,   // [B*4096][768] bf16, col = h*128+d
    const float* __restrict__ offawp,// [KS1][8192][72] f32 K-partials
    const float* __restrict__ refp,  // [8192][2] f32
    u16* __restrict__ out) {
  const int wq   = blockIdx.x * 4 + (threadIdx.x >> 6);  // 0..24575
  const int lane = threadIdx.x & 63;
  const int row  = wq / 3;
  const int h0   = (wq % 3) * 2;      // 0,2,4
  const int b    = row >> 12;
  const float* pr = offawp + (size_t)row*72;
  float rx = refp[(size_t)row*2]   * 64.f - 0.5f;
  float ry = refp[(size_t)row*2+1] * 64.f - 0.5f;

  float wts[2][16]; int offs[2][16];
  #pragma unroll
  for (int s = 0; s < 2; ++s) {
    const int h = h0 + s;
    float ob[8], aw4[4];
    #pragma unroll
    for (int k = 0; k < 8; ++k) {
      float v = 0.f;
      #pragma unroll
      for (int z = 0; z < KS1; ++z) v += pr[(size_t)z*NROWS*72 + h*8 + k];
      ob[k] = v;
    }
    #pragma unroll
    for (int k = 0; k < 4; ++k) {
      float v = 0.f;
      #pragma unroll
      for (int z = 0; z < KS1; ++z) v += pr[(size_t)z*NROWS*72 + 48 + h*4 + k];
      aw4[k] = v;
    }
    float mx = fmaxf(fmaxf(aw4[0],aw4[1]), fmaxf(aw4[2],aw4[3]));
    float e0 = __expf(aw4[0]-mx), e1 = __expf(aw4[1]-mx), e2 = __expf(aw4[2]-mx), e3 = __expf(aw4[3]-mx);
    float rs = 1.f / (e0+e1+e2+e3);
    float awt[4] = {e0*rs, e1*rs, e2*rs, e3*rs};
    #pragma unroll
    for (int p = 0; p < 4; ++p) {
      float px = rx + ob[p*2];
      float py = ry + ob[p*2+1];
      float x0f = floorf(px), y0f = floorf(py);
      float fx = px - x0f, fy = py - y0f;
      int x0 = (int)x0f, y0 = (int)y0f;
      #pragma unroll
      for (int dy = 0; dy < 2; ++dy)
        #pragma unroll
        for (int dx = 0; dx < 2; ++dx) {
          int yi = y0 + dy, xi = x0 + dx;
          bool valid = (yi >= 0) & (yi < 64) & (xi >= 0) & (xi < 64);
          float wt = (dy ? fy : 1.f-fy) * (dx ? fx : 1.f-fx) * awt[p];
          wts[s][p*4+dy*2+dx] = valid ? wt : 0.f;
          int yc = min(max(yi, 0), 63), xc = min(max(xi, 0), 63);
          offs[s][p*4+dy*2+dx] = (yc*64 + xc) * 384;
        }
    }
  }
  const u32* vbase = (const u32*)value + (size_t)b*4096*384 + h0*64 + lane;
  u32 vals[2][16];
  #pragma unroll
  for (int s = 0; s < 2; ++s)
    #pragma unroll
    for (int i = 0; i < 16; ++i)
      vals[s][i] = (vbase + s*64)[offs[s][i]];   // 32 loads in flight
  #pragma unroll
  for (int s = 0; s < 2; ++s) {
    float accx = 0.f, accy = 0.f;
    #pragma unroll
    for (int i = 0; i < 16; ++i) {
      accx += wts[s][i] * bf2f((u16)(vals[s][i] & 0xffffu));
      accy += wts[s][i] * bf2f((u16)(vals[s][i] >> 16));
    }
    ((u32*)out)[(size_t)row*384 + (h0+s)*64 + lane] = (u32)f2bf(accx) | ((u32)f2bf(accy) << 16);
  }
}

extern "C" void kernel_launch(void* const* d_in, const int* in_sizes, int n_in,
                              void* d_out, int out_size, void* d_ws, size_t ws_size,
                              hipStream_t stream) {
  const float* x       = (const float*)d_in[0];
  const float* refp    = (const float*)d_in[1];
  const float* feat    = (const float*)d_in[2];
  const float* qn_w    = (const float*)d_in[5];
  const float* qn_b    = (const float*)d_in[6];
  const float* fn_w    = (const float*)d_in[7];
  const float* fn_b    = (const float*)d_in[8];
  const float* gamma   = (const float*)d_in[9];
  const float* w_value = (const float*)d_in[10];
  const float* b_value = (const float*)d_in[11];
  const float* w_off   = (const float*)d_in[12];
  const float* b_off   = (const float*)d_in[13];
  const float* w_attn  = (const float*)d_in[14];
  const float* b_attn  = (const float*)d_in[15];
  const float* w_out   = (const float*)d_in[16];
  const float* b_out   = (const float*)d_in[17];

  char* p = (char*)d_ws;
  const size_t act = (size_t)NROWS * CDIM * 2;       // 12.58 MB
  u16* q_bf   = (u16*)p; p += act;
  u16* f_bf   = (u16*)p; p += act;
  u16* val_bf = (u16*)p; p += act;
  u16* wvT    = (u16*)p; p += (size_t)CDIM*CDIM*2;
  u16* woT    = (u16*)p; p += (size_t)CDIM*CDIM*2;
  u16* woaT   = (u16*)p; p += (size_t)128*CDIM*2;
  float* offawp = (float*)p; p += (size_t)KS1*NROWS*72*4;
  u16* samp_bf = q_bf;   // q_bf dead after gemm01; reuse

  pre_kernel<<<dim3(2*NROWS + 1728), 192, 0, stream>>>(
      x, feat, qn_w, qn_b, fn_w, fn_b, w_value, w_out, w_off, w_attn,
      q_bf, f_bf, wvT, woT, woaT);
  gemm01<<<dim3(64, 14), 256, 0, stream>>>(
      f_bf, q_bf, wvT, woaT, val_bf, offawp, b_value, b_off, b_attn);
  sample_kernel<<<dim3(6144), 256, 0, stream>>>(val_bf, offawp, refp, samp_bf);
  gemm2<<<dim3(64, 6), 256, 0, stream>>>(samp_bf, woT, (float*)d_out, b_out, x, gamma);
}